// Round 5
// baseline (46.227 us; speedup 1.0000x reference)
//
#include <hip/hip_runtime.h>

#define HH 160
#define WW 160
#define CC 32
#define NN 8
#define PIX (HH * WW)   // 25600 = 400 tiles of 64

typedef float f32x2 __attribute__((ext_vector_type(2)));

// Block: 256 threads = 4 channel-groups x 64 flattened pixels.
// Each thread: 8 channels of one pixel, channel loop unrolled x2.
// Kernel taps (36/pixel, channel-invariant) staged once into LDS, then held
// in 36 VGPRs. __launch_bounds__(256,6) caps VGPR ~85 -> 6 waves/SIMD
// (vs 4 in all prior rounds) to test the latency/occupancy theory.
__global__ __launch_bounds__(256, 6) void pixelconv_k(
    const float* __restrict__ feature,   // [8,32,160,160]
    const float* __restrict__ kern,      // [8,36,160,160]
    float* __restrict__ out)             // [8,32,320,320]
{
    const int tile = blockIdx.x;        // 0..399
    const int n    = blockIdx.y;        // 0..7
    const int t    = threadIdx.x;       // 0..255
    const int lane = t & 63;            // pixel within tile
    const int cg   = t >> 6;            // 0..3 channel group (8 ch each)
    const int pixbase = tile * 64;

    // ---- stage kernel[n][0:36][pixbase:pixbase+64] into LDS (9 KB) ----
    __shared__ float kv_lds[36 * 64];
    const float* kbase = kern + (size_t)n * 36 * PIX + pixbase;
    #pragma unroll
    for (int r = 0; r < 9; ++r) {
        const int idx = t + r * 256;    // idx = j*64 + lp, coalesced per wave
        kv_lds[idx] = kbase[(size_t)(idx >> 6) * PIX + (idx & 63)];
    }
    __syncthreads();

    // per-thread copy of the 36 taps for its pixel (bank-conflict-free)
    float kv[36];
    #pragma unroll
    for (int j = 0; j < 36; ++j) kv[j] = kv_lds[j * 64 + lane];

    const int pix = pixbase + lane;     // PIX = 400*64 exactly, no guard
    const int h = pix / WW;
    const int w = pix - h * WW;
    const bool hm = (h > 0), hp = (h < HH - 1);
    const bool wm = (w > 0), wp = (w < WW - 1);

    const float* fc = feature + ((size_t)(n * CC + cg * 8)) * PIX + pix;
    float* oc = out + ((size_t)(n * CC + cg * 8)) * 4 * PIX
                    + (size_t)(2 * h) * (2 * WW) + 2 * w;

    #pragma unroll 2
    for (int i = 0; i < 8; ++i) {
        // 9 taps, k = dx*3 + dy -> feature[h+dy-1][w+dx-1], imm offsets off fc
        float f[9];
        #pragma unroll
        for (int dx = 0; dx < 3; ++dx) {
            #pragma unroll
            for (int dy = 0; dy < 3; ++dy) {
                const bool ok = (dy != 0 || hm) && (dy != 2 || hp) &&
                                (dx != 0 || wm) && (dx != 2 || wp);
                f[dx * 3 + dy] = ok ? fc[(dy - 1) * WW + (dx - 1)] : 0.0f;
            }
        }

        float a0 = 0.f, a1 = 0.f, a2 = 0.f, a3 = 0.f;
        #pragma unroll
        for (int k = 0; k < 9; ++k) {
            a0 = fmaf(f[k], kv[4 * k + 0], a0);
            a1 = fmaf(f[k], kv[4 * k + 1], a1);
            a2 = fmaf(f[k], kv[4 * k + 2], a2);
            a3 = fmaf(f[k], kv[4 * k + 3], a3);
        }

        // pixel shuffle: s = r1*2 + r2 -> rows 2h (offset 0) and 2h+1 (+320)
        *(f32x2*)(oc)            = (f32x2){a0, a1};
        *(f32x2*)(oc + 2 * WW)   = (f32x2){a2, a3};

        fc += PIX;          // next channel's feature plane
        oc += (size_t)4 * PIX;  // next channel's output plane
    }
}

extern "C" void kernel_launch(void* const* d_in, const int* in_sizes, int n_in,
                              void* d_out, int out_size, void* d_ws, size_t ws_size,
                              hipStream_t stream) {
    const float* feature = (const float*)d_in[0];
    const float* kern    = (const float*)d_in[1];
    float* out           = (float*)d_out;

    dim3 grid(PIX / 64, NN, 1);   // (400, 8)
    pixelconv_k<<<grid, 256, 0, stream>>>(feature, kern, out);
}

// Round 6
// 45.261 us; speedup vs baseline: 1.0214x; 1.0214x over previous
//
#include <hip/hip_runtime.h>

#define HH 160
#define WW 160
#define CC 32
#define NN 8
#define PIX (HH * WW)   // 25600 = 400 tiles of 64

typedef float f32x2 __attribute__((ext_vector_type(2)));

// Block: 256 threads = 4 channel-groups x 64 flattened pixels.
// Each thread: 8 channels of one pixel, explicit 2-deep software pipeline on
// the channel loop (taps for c+1 in flight while c computes). Kernel taps
// staged via LDS into 36 VGPRs (channel-invariant). Output written with
// nontemporal stores: keeps the 105 MB write stream out of L2/L3 so inputs
// stay L3-resident across replays and HBM sees a clean write stream.
__global__ __launch_bounds__(256, 6) void pixelconv_k(
    const float* __restrict__ feature,   // [8,32,160,160]
    const float* __restrict__ kern,      // [8,36,160,160]
    float* __restrict__ out)             // [8,32,320,320]
{
    const int tile = blockIdx.x;        // 0..399
    const int n    = blockIdx.y;        // 0..7
    const int t    = threadIdx.x;       // 0..255
    const int lane = t & 63;            // pixel within tile
    const int cg   = t >> 6;            // 0..3 channel group (8 ch each)
    const int pixbase = tile * 64;

    // ---- stage kernel[n][0:36][pixbase:pixbase+64] into LDS (9 KB) ----
    __shared__ float kv_lds[36 * 64];
    const float* kbase = kern + (size_t)n * 36 * PIX + pixbase;
    #pragma unroll
    for (int r = 0; r < 9; ++r) {
        const int idx = t + r * 256;    // idx = j*64 + lp, coalesced per wave
        kv_lds[idx] = kbase[(size_t)(idx >> 6) * PIX + (idx & 63)];
    }
    __syncthreads();

    // per-thread copy of the 36 taps for its pixel (bank-conflict-free)
    float kv[36];
    #pragma unroll
    for (int j = 0; j < 36; ++j) kv[j] = kv_lds[j * 64 + lane];

    const int pix = pixbase + lane;     // PIX = 400*64 exactly, no guard
    const int h = pix / WW;
    const int w = pix - h * WW;
    const bool hm = (h > 0), hp = (h < HH - 1);
    const bool wm = (w > 0), wp = (w < WW - 1);

    const float* fc = feature + ((size_t)(n * CC + cg * 8)) * PIX + pix;
    float* oc = out + ((size_t)(n * CC + cg * 8)) * 4 * PIX
                    + (size_t)(2 * h) * (2 * WW) + 2 * w;

    // tap loader: k = dx*3 + dy -> feature[h+dy-1][w+dx-1] (imm offsets)
    auto load_taps = [&](const float* p, float* f) {
        #pragma unroll
        for (int dx = 0; dx < 3; ++dx) {
            #pragma unroll
            for (int dy = 0; dy < 3; ++dy) {
                const bool ok = (dy != 0 || hm) && (dy != 2 || hp) &&
                                (dx != 0 || wm) && (dx != 2 || wp);
                f[dx * 3 + dy] = ok ? p[(dy - 1) * WW + (dx - 1)] : 0.0f;
            }
        }
    };

    float fcur[9], fnxt[9];
    load_taps(fc, fcur);                // prologue: channel 0 taps in flight

    #pragma unroll
    for (int i = 0; i < 8; ++i) {
        if (i < 7) load_taps(fc + PIX, fnxt);   // next channel's loads issued
        fc += PIX;

        float a0 = 0.f, a1 = 0.f, a2 = 0.f, a3 = 0.f;
        #pragma unroll
        for (int k = 0; k < 9; ++k) {
            a0 = fmaf(fcur[k], kv[4 * k + 0], a0);
            a1 = fmaf(fcur[k], kv[4 * k + 1], a1);
            a2 = fmaf(fcur[k], kv[4 * k + 2], a2);
            a3 = fmaf(fcur[k], kv[4 * k + 3], a3);
        }

        // pixel shuffle: s = r1*2 + r2 -> rows 2h (offset 0) and 2h+1 (+320)
        __builtin_nontemporal_store((f32x2){a0, a1}, (f32x2*)oc);
        __builtin_nontemporal_store((f32x2){a2, a3}, (f32x2*)(oc + 2 * WW));
        oc += (size_t)4 * PIX;          // next channel's output plane

        #pragma unroll
        for (int k = 0; k < 9; ++k) fcur[k] = fnxt[k];
    }
}

extern "C" void kernel_launch(void* const* d_in, const int* in_sizes, int n_in,
                              void* d_out, int out_size, void* d_ws, size_t ws_size,
                              hipStream_t stream) {
    const float* feature = (const float*)d_in[0];
    const float* kern    = (const float*)d_in[1];
    float* out           = (float*)d_out;

    dim3 grid(PIX / 64, NN, 1);   // (400, 8)
    pixelconv_k<<<grid, 256, 0, stream>>>(feature, kern, out);
}

// Round 7
// 32.344 us; speedup vs baseline: 1.4292x; 1.3994x over previous
//
#include <hip/hip_runtime.h>

#define HH 160
#define WW 160
#define CC 32
#define NN 8
#define PIX (HH * WW)   // 25600

typedef float f32x2 __attribute__((ext_vector_type(2)));

// Block: 640 threads = 4 channel-groups x 160 w (one FULL feature row).
// Each thread: 8 channels of one pixel. Every 2560 B output region
// (rows 2h,2h+1 of one (n,c) plane) is written entirely by this block,
// address-contiguously -> coherent HBM write stream. Kernel taps for the
// whole row staged in LDS (36x160 = 23 KB), then 36 VGPRs per thread.
// h is XCD-chunk-swizzled (8 chunks of 20 rows) so each XCD writes a
// contiguous h-band of every channel plane.
__global__ __launch_bounds__(640, 5) void pixelconv_k(
    const float* __restrict__ feature,   // [8,32,160,160]
    const float* __restrict__ kern,      // [8,36,160,160]
    float* __restrict__ out)             // [8,32,320,320]
{
    const int bx = blockIdx.x;                 // 0..159
    const int h  = (bx & 7) * 20 + (bx >> 3);  // XCD-chunked h swizzle
    const int n  = blockIdx.y;                 // 0..7
    const int t  = threadIdx.x;                // 0..639
    const int wl = t % 160;                    // w position
    const int cg = t / 160;                    // 0..3 channel group (8 ch)

    // ---- stage kernel[n][0:36][h][0:160] into LDS (36*160 floats) ----
    __shared__ float kv_lds[36 * 160];
    const float* kbase = kern + (size_t)n * 36 * PIX + (size_t)h * WW;
    #pragma unroll
    for (int r = 0; r < 9; ++r) {
        const int idx = t + r * 640;           // 5760 = 9 * 640 exactly
        const int j   = idx / 160;
        const int ws  = idx - j * 160;
        kv_lds[idx] = kbase[(size_t)j * PIX + ws];
    }
    __syncthreads();

    // per-thread copy of the 36 taps for its pixel
    float kv[36];
    #pragma unroll
    for (int j = 0; j < 36; ++j) kv[j] = kv_lds[j * 160 + wl];

    const bool hm = (h > 0), hp = (h < HH - 1);
    const bool wm = (wl > 0), wp = (wl < WW - 1);

    const float* fc = feature + ((size_t)(n * CC + cg * 8)) * PIX
                              + (size_t)h * WW + wl;
    float* oc = out + ((size_t)(n * CC + cg * 8)) * 4 * PIX
                    + (size_t)(2 * h) * (2 * WW) + 2 * wl;

    #pragma unroll 2
    for (int i = 0; i < 8; ++i) {
        // 9 taps, k = dx*3 + dy -> feature[h+dy-1][w+dx-1], imm offsets
        float f[9];
        #pragma unroll
        for (int dx = 0; dx < 3; ++dx) {
            #pragma unroll
            for (int dy = 0; dy < 3; ++dy) {
                const bool ok = (dy != 0 || hm) && (dy != 2 || hp) &&
                                (dx != 0 || wm) && (dx != 2 || wp);
                f[dx * 3 + dy] = ok ? fc[(dy - 1) * WW + (dx - 1)] : 0.0f;
            }
        }

        float a0 = 0.f, a1 = 0.f, a2 = 0.f, a3 = 0.f;
        #pragma unroll
        for (int k = 0; k < 9; ++k) {
            a0 = fmaf(f[k], kv[4 * k + 0], a0);
            a1 = fmaf(f[k], kv[4 * k + 1], a1);
            a2 = fmaf(f[k], kv[4 * k + 2], a2);
            a3 = fmaf(f[k], kv[4 * k + 3], a3);
        }

        // pixel shuffle: s = r1*2 + r2 -> rows 2h (offset 0), 2h+1 (+320)
        *(f32x2*)(oc)          = (f32x2){a0, a1};
        *(f32x2*)(oc + 2 * WW) = (f32x2){a2, a3};

        fc += PIX;               // next channel's feature plane
        oc += (size_t)4 * PIX;   // next channel's output plane
    }
}

extern "C" void kernel_launch(void* const* d_in, const int* in_sizes, int n_in,
                              void* d_out, int out_size, void* d_ws, size_t ws_size,
                              hipStream_t stream) {
    const float* feature = (const float*)d_in[0];
    const float* kern    = (const float*)d_in[1];
    float* out           = (float*)d_out;

    dim3 grid(HH, NN, 1);   // (160, 8)
    pixelconv_k<<<grid, 640, 0, stream>>>(feature, kern, out);
}